// Round 5
// baseline (405.528 us; speedup 1.0000x reference)
//
#include <hip/hip_runtime.h>
#include <hip/hip_cooperative_groups.h>
#include <math.h>

namespace cg = cooperative_groups;

#define BATCH 8
#define CCH   256
#define TT    32
#define HWSZ  784      // 28*28
#define HID   512
#define EMB   32
#define KBINS 4
#define SCALEF 5.0f
#define EPSN  1e-12f

// Phase C task count: B * C * 196 float4 positions
#define NTASK  (BATCH * CCH * 196)          // 401408
#define NTHREADS (256 * 1024)               // grid threads = 262144

// ---------------------------------------------------------------------------
// Single cooperative kernel: 256 blocks x 1024 threads (grid-resident).
//  Phase A: block = (b,t): pool x over HW -> fc1+hswish -> fc2 -> embds[b,:,t]
//  grid sync
//  Phase B: blocks 0..7 (block b): l2norm -> neighbor sims -> rank-count
//           3rd-smallest threshold -> grouping -> centers -> softmax weights
//           -> per-group normalized nw[b,t,k]
//  grid sync
//  Phase C: all threads: out[b,c,k,hw4] = sum_t x[b,c,t,hw4] * nw[b,t,k]
// ---------------------------------------------------------------------------
__global__ __launch_bounds__(1024) void fused_kernel(
        const float* __restrict__ x,
        const float* __restrict__ W1, const float* __restrict__ b1,
        const float* __restrict__ W2, const float* __restrict__ b2,
        float* __restrict__ embds, float* __restrict__ nw,
        float* __restrict__ out) {
    cg::grid_group grid = cg::this_grid();

    __shared__ float pcol[CCH];
    __shared__ float hcol[HID];
    __shared__ float se[EMB][TT + 1];
    __shared__ float ns[TT];
    __shared__ float colinv[TT];
    __shared__ float thr_sh;
    __shared__ float cs[EMB][KBINS];
    __shared__ float wts[TT][KBINS];
    __shared__ float gsize[KBINS];
    __shared__ float kfac[KBINS];
    __shared__ int   gid[TT];
    __shared__ float wtab[BATCH * TT * KBINS];   // 1024 floats

    const int tid  = threadIdx.x;
    const int wave = tid >> 6;
    const int lane = tid & 63;

    // ---------------- Phase A ----------------
    {
        const int b = blockIdx.x >> 5;           // blockIdx = b*TT + t
        const int t = blockIdx.x & 31;

        // pool: pcol[c] = mean(x[b,c,t,:,:]) — wave per channel
        for (int c = wave; c < CCH; c += 16) {
            const float4* xp = (const float4*)(x + ((size_t)((b * CCH + c) * TT + t)) * HWSZ);
            float s = 0.f;
            for (int f = lane; f < 196; f += 64) {
                float4 v = xp[f];
                s += v.x + v.y + v.z + v.w;
            }
#pragma unroll
            for (int off = 32; off > 0; off >>= 1) s += __shfl_down(s, off);
            if (lane == 0) pcol[c] = s * (1.0f / 784.0f);
        }
        __syncthreads();

        // fc1 + hswish
        if (tid < HID) {
            const float4* w = (const float4*)(W1 + (size_t)tid * CCH);
            float acc = 0.f;
#pragma unroll 8
            for (int j = 0; j < CCH / 4; j++) {
                float4 wv = w[j];
                acc += wv.x * pcol[4 * j] + wv.y * pcol[4 * j + 1]
                     + wv.z * pcol[4 * j + 2] + wv.w * pcol[4 * j + 3];
            }
            acc += b1[tid];
            float r = fminf(fmaxf(acc + 3.0f, 0.0f), 6.0f);
            hcol[tid] = acc * r * (1.0f / 6.0f);
        }
        __syncthreads();

        // fc2: 32 threads per e
        {
            const int e = tid >> 5;
            const int l = tid & 31;
            const float* w = W2 + (size_t)e * HID;
            float acc = 0.f;
#pragma unroll
            for (int j = 0; j < HID / 32; j++) acc += w[l + 32 * j] * hcol[l + 32 * j];
            acc += __shfl_down(acc, 16);
            acc += __shfl_down(acc, 8);
            acc += __shfl_down(acc, 4);
            acc += __shfl_down(acc, 2);
            acc += __shfl_down(acc, 1);
            if (l == 0) embds[((size_t)b * EMB + e) * TT + t] = acc + b2[e];
        }
    }

    grid.sync();

    // ---------------- Phase B ----------------
    if (blockIdx.x < BATCH) {
        const int b = blockIdx.x;

        // load embds column-major tile: se[e][t]; tid covers all 1024 elements
        se[tid >> 5][tid & 31] = embds[(size_t)b * EMB * TT + tid];
        __syncthreads();

        if (tid < TT) {
            float s = 0.f;
            for (int e = 0; e < EMB; e++) { float v = se[e][tid]; s += v * v; }
            colinv[tid] = 1.0f / fmaxf(sqrtf(s), EPSN);
        }
        __syncthreads();
        se[tid >> 5][tid & 31] *= colinv[tid & 31];
        __syncthreads();

        if (tid < TT - 1) {
            float s = 0.f;
            for (int e = 0; e < EMB; e++) s += se[e][tid] * se[e][tid + 1];
            ns[tid] = s;
        }
        __syncthreads();

        // threshold = stable-rank-2 element (3rd smallest incl. duplicates)
        if (tid < TT - 1) {
            float v = ns[tid];
            int pos = 0;
            for (int j = 0; j < TT - 1; j++) {
                float u = ns[j];
                pos += (u < v) || (u == v && j < tid);
            }
            if (pos == KBINS - 2) thr_sh = v;
        }
        __syncthreads();

        if (tid < TT) {
            float thr = thr_sh;
            int g = 0;
            for (int s = 1; s <= tid; s++) g += !(ns[s - 1] > thr);
            gid[tid] = g;
        }
        __syncthreads();
        if (tid < KBINS) {
            float c = 0.f;
            for (int t = 0; t < TT; t++) c += (gid[t] == tid);
            gsize[tid] = c;
        }
        __syncthreads();

        if (tid < EMB * KBINS) {
            int e = tid >> 2, k = tid & 3;
            float s = 0.f;
            for (int t = 0; t < TT; t++) if (gid[t] == k) s += se[e][t];
            cs[e][k] = s / gsize[k];
        }
        __syncthreads();
        if (tid < KBINS) {
            float s = 0.f;
            for (int e = 0; e < EMB; e++) { float v = cs[e][tid]; s += v * v; }
            kfac[tid] = 1.0f / fmaxf(sqrtf(s), EPSN);
        }
        __syncthreads();
        if (tid < EMB * KBINS) {
            int e = tid >> 2, k = tid & 3;
            cs[e][k] *= kfac[k];
        }
        __syncthreads();

        if (tid < TT * KBINS) {
            int t = tid >> 2, k = tid & 3;
            float s = 0.f;
            for (int e = 0; e < EMB; e++) s += se[e][t] * cs[e][k];
            wts[t][k] = s * SCALEF;
        }
        __syncthreads();
        if (tid < TT) {
            float m = wts[tid][0];
            for (int k = 1; k < KBINS; k++) m = fmaxf(m, wts[tid][k]);
            float ex[KBINS]; float sum = 0.f;
            for (int k = 0; k < KBINS; k++) { ex[k] = expf(wts[tid][k] - m); sum += ex[k]; }
            float inv = 1.0f / sum;
            for (int k = 0; k < KBINS; k++) wts[tid][k] = ex[k] * inv;
        }
        __syncthreads();
        if (tid < KBINS) {
            float s = 0.f;
            for (int t = 0; t < TT; t++) s += wts[t][tid];
            kfac[tid] = (s > 0.f) ? (1.0f / s) : 1.0f;
        }
        __syncthreads();
        if (tid < TT * KBINS) {
            int t = tid >> 2, k = tid & 3;
            nw[((size_t)b * TT + t) * KBINS + k] = wts[t][k] * kfac[k];
        }
    }

    grid.sync();

    // ---------------- Phase C ----------------
    // broadcast full nw table (1024 floats) into LDS
    wtab[tid] = nw[tid];
    __syncthreads();

    const unsigned idx0 = blockIdx.x * 1024 + tid;   // [0, 262144)
#pragma unroll
    for (int rep = 0; rep < 2; rep++) {
        unsigned task = idx0 + rep * NTHREADS;
        if (task >= NTASK) break;
        const unsigned b = task / (CCH * 196);
        const unsigned rem = task - b * (CCH * 196);
        const unsigned c = rem / 196;
        const unsigned f = rem - c * 196;
        const float4* xp = (const float4*)(x + ((size_t)(b * CCH + c) * TT) * HWSZ);
        const float* wrow = &wtab[b * TT * KBINS];
        float4 acc[KBINS];
#pragma unroll
        for (int k = 0; k < KBINS; k++) { acc[k].x = 0.f; acc[k].y = 0.f; acc[k].z = 0.f; acc[k].w = 0.f; }
#pragma unroll 8
        for (int t = 0; t < TT; t++) {
            float4 v = xp[t * 196 + f];
#pragma unroll
            for (int k = 0; k < KBINS; k++) {
                float wk = wrow[t * KBINS + k];
                acc[k].x += v.x * wk;
                acc[k].y += v.y * wk;
                acc[k].z += v.z * wk;
                acc[k].w += v.w * wk;
            }
        }
        float4* op = (float4*)(out + ((size_t)(b * CCH + c) * KBINS) * HWSZ);
#pragma unroll
        for (int k = 0; k < KBINS; k++) op[k * 196 + f] = acc[k];
    }
}

extern "C" void kernel_launch(void* const* d_in, const int* in_sizes, int n_in,
                              void* d_out, int out_size, void* d_ws, size_t ws_size,
                              hipStream_t stream) {
    const float* x  = (const float*)d_in[0];
    const float* W1 = (const float*)d_in[1];
    const float* b1 = (const float*)d_in[2];
    const float* W2 = (const float*)d_in[3];
    const float* b2 = (const float*)d_in[4];
    float* out = (float*)d_out;

    float* ws    = (float*)d_ws;
    float* embds = ws;                         // B*EMB*T = 8192
    float* nw    = embds + BATCH * EMB * TT;   // B*T*K   = 1024

    void* args[] = { (void*)&x, (void*)&W1, (void*)&b1, (void*)&W2, (void*)&b2,
                     (void*)&embds, (void*)&nw, (void*)&out };
    hipLaunchCooperativeKernel((const void*)fused_kernel,
                               dim3(BATCH * TT), dim3(1024), args, 0, stream);
}

// Round 6
// 344.861 us; speedup vs baseline: 1.1759x; 1.1759x over previous
//
#include <hip/hip_runtime.h>
#include <math.h>

#define BATCH 8
#define CCH   256
#define TT    32
#define HWSZ  784      // 28*28
#define HID   512
#define EMB   32
#define KBINS 4
#define SCALEF 5.0f
#define EPSN  1e-12f

// ---------------------------------------------------------------------------
// Kernel 1: pooled[b][t][c] = mean over 784 of x[b,c,t,:,:]
// 2048 blocks x 256 threads; one wave per (b,c,t) row; 32 waves/CU.
// Straight-line loads: 3 uniform float4 + 1 exec-masked tail (196 = 3*64+4)
// so all 3-4 loads issue back-to-back per lane (latency hiding via TLP+ILP).
// ---------------------------------------------------------------------------
__global__ __launch_bounds__(256) void pool_kernel(
        const float* __restrict__ x, float* __restrict__ pooled) {
    const int wave = threadIdx.x >> 6;
    const int lane = threadIdx.x & 63;
    const int row  = blockIdx.x * 4 + wave;      // row = (b*CCH + c)*TT + t
    const float4* xp = (const float4*)(x + (size_t)row * HWSZ);

    float4 v0 = xp[lane];
    float4 v1 = xp[lane + 64];
    float4 v2 = xp[lane + 128];
    float s = v0.x + v0.y + v0.z + v0.w
            + v1.x + v1.y + v1.z + v1.w
            + v2.x + v2.y + v2.z + v2.w;
    if (lane < 4) {                               // tail: elements 768..783
        float4 v3 = xp[lane + 192];
        s += v3.x + v3.y + v3.z + v3.w;
    }
#pragma unroll
    for (int off = 32; off > 0; off >>= 1) s += __shfl_down(s, off);
    if (lane == 0) {
        const int t = row & 31;
        const int c = (row >> 5) & 255;
        const int b = row >> 13;
        pooled[((size_t)(b * TT + t)) * CCH + c] = s * (1.0f / 784.0f);
    }
}

// ---------------------------------------------------------------------------
// Kernel 2 (fused fc1+fc2): block per (b,t), 512 threads.
//   fc1: thread per hid — dot-256 of W1 row vs LDS pooled column, hswish.
//   fc2: 16 threads per e — dot-512 vs LDS h, shuffle reduce.
// W1/W2 stream from L2 (512 KB + 64 KB per block, 256 blocks -> ~147 MB L2).
// ---------------------------------------------------------------------------
__global__ __launch_bounds__(512) void fc_kernel(
        const float* __restrict__ W1, const float* __restrict__ b1,
        const float* __restrict__ W2, const float* __restrict__ b2,
        const float* __restrict__ pooled, float* __restrict__ embds) {
    __shared__ float pc[CCH];
    __shared__ float hcol[HID];

    const int b = blockIdx.x >> 5;               // blockIdx = b*TT + t
    const int t = blockIdx.x & 31;
    const int tid = threadIdx.x;

    if (tid < CCH / 4)
        ((float4*)pc)[tid] = ((const float4*)(pooled + ((size_t)(b * TT + t)) * CCH))[tid];
    __syncthreads();

    // fc1 + hswish
    {
        const float4* w = (const float4*)(W1 + (size_t)tid * CCH);
        float acc = 0.f;
#pragma unroll 8
        for (int j = 0; j < CCH / 4; j++) {
            float4 wv = w[j];
            acc += wv.x * pc[4 * j] + wv.y * pc[4 * j + 1]
                 + wv.z * pc[4 * j + 2] + wv.w * pc[4 * j + 3];
        }
        acc += b1[tid];
        float r = fminf(fmaxf(acc + 3.0f, 0.0f), 6.0f);
        hcol[tid] = acc * r * (1.0f / 6.0f);
    }
    __syncthreads();

    // fc2: 16 threads per embedding dim
    {
        const int e = tid >> 4;                  // 0..31
        const int l = tid & 15;
        const float* w = W2 + (size_t)e * HID;
        float acc = 0.f;
#pragma unroll
        for (int j = 0; j < HID / 16; j++) acc += w[l + 16 * j] * hcol[l + 16 * j];
        acc += __shfl_down(acc, 8);
        acc += __shfl_down(acc, 4);
        acc += __shfl_down(acc, 2);
        acc += __shfl_down(acc, 1);
        if (l == 0) embds[((size_t)b * EMB + e) * TT + t] = acc + b2[e];
    }
}

// ---------------------------------------------------------------------------
// Kernel 3: one block per batch — fully parallel middle.
// ---------------------------------------------------------------------------
__global__ void group_kernel(const float* __restrict__ embds, float* __restrict__ nw) {
    __shared__ float se[EMB][TT + 1];
    __shared__ float ns[TT];
    __shared__ float colinv[TT];
    __shared__ float thr_sh;
    __shared__ float cs[EMB][KBINS];
    __shared__ float wts[TT][KBINS];
    __shared__ float gsize[KBINS];
    __shared__ float kfac[KBINS];
    __shared__ int   gid[TT];

    const int b   = blockIdx.x;
    const int tid = threadIdx.x;

    for (int i = tid; i < EMB * TT; i += 256)
        se[i >> 5][i & 31] = embds[(size_t)b * EMB * TT + i];
    __syncthreads();

    if (tid < TT) {
        float s = 0.f;
        for (int e = 0; e < EMB; e++) { float v = se[e][tid]; s += v * v; }
        colinv[tid] = 1.0f / fmaxf(sqrtf(s), EPSN);
    }
    __syncthreads();
    for (int i = tid; i < EMB * TT; i += 256) {
        int e = i >> 5, t = i & 31;
        se[e][t] *= colinv[t];
    }
    __syncthreads();

    if (tid < TT - 1) {
        float s = 0.f;
        for (int e = 0; e < EMB; e++) s += se[e][tid] * se[e][tid + 1];
        ns[tid] = s;
    }
    __syncthreads();

    // threshold = stable-rank-2 element (3rd smallest incl. duplicates)
    if (tid < TT - 1) {
        float v = ns[tid];
        int pos = 0;
        for (int j = 0; j < TT - 1; j++) {
            float u = ns[j];
            pos += (u < v) || (u == v && j < tid);
        }
        if (pos == KBINS - 2) thr_sh = v;
    }
    __syncthreads();

    if (tid < TT) {
        float thr = thr_sh;
        int g = 0;
        for (int s = 1; s <= tid; s++) g += !(ns[s - 1] > thr);
        gid[tid] = g;
    }
    __syncthreads();
    if (tid < KBINS) {
        float c = 0.f;
        for (int t = 0; t < TT; t++) c += (gid[t] == tid);
        gsize[tid] = c;
    }
    __syncthreads();

    if (tid < EMB * KBINS) {
        int e = tid >> 2, k = tid & 3;
        float s = 0.f;
        for (int t = 0; t < TT; t++) if (gid[t] == k) s += se[e][t];
        cs[e][k] = s / gsize[k];
    }
    __syncthreads();
    if (tid < KBINS) {
        float s = 0.f;
        for (int e = 0; e < EMB; e++) { float v = cs[e][tid]; s += v * v; }
        kfac[tid] = 1.0f / fmaxf(sqrtf(s), EPSN);
    }
    __syncthreads();
    if (tid < EMB * KBINS) {
        int e = tid >> 2, k = tid & 3;
        cs[e][k] *= kfac[k];
    }
    __syncthreads();

    if (tid < TT * KBINS) {
        int t = tid >> 2, k = tid & 3;
        float s = 0.f;
        for (int e = 0; e < EMB; e++) s += se[e][t] * cs[e][k];
        wts[t][k] = s * SCALEF;
    }
    __syncthreads();
    if (tid < TT) {
        float m = wts[tid][0];
        for (int k = 1; k < KBINS; k++) m = fmaxf(m, wts[tid][k]);
        float ex[KBINS]; float sum = 0.f;
        for (int k = 0; k < KBINS; k++) { ex[k] = expf(wts[tid][k] - m); sum += ex[k]; }
        float inv = 1.0f / sum;
        for (int k = 0; k < KBINS; k++) wts[tid][k] = ex[k] * inv;
    }
    __syncthreads();
    if (tid < KBINS) {
        float s = 0.f;
        for (int t = 0; t < TT; t++) s += wts[t][tid];
        kfac[tid] = (s > 0.f) ? (1.0f / s) : 1.0f;
    }
    __syncthreads();
    if (tid < TT * KBINS) {
        int t = tid >> 2, k = tid & 3;
        nw[((size_t)b * TT + t) * KBINS + k] = wts[t][k] * kfac[k];
    }
}

// ---------------------------------------------------------------------------
// Kernel 4: out[b,c,k,hw4] = sum_t x[b,c,t,hw4] * nw[b,t,k]
// 3136 blocks x 128 threads; x re-read is L3-resident (FETCH evidence R5).
// ---------------------------------------------------------------------------
__global__ __launch_bounds__(128) void out_kernel(
        const float* __restrict__ x, const float* __restrict__ nw,
        float* __restrict__ out) {
    __shared__ float w[TT * KBINS];
    const int b = blockIdx.x / 392;
    const unsigned idx = (blockIdx.x % 392) * 128 + threadIdx.x;   // [0, 50176)
    w[threadIdx.x] = nw[(size_t)b * TT * KBINS + threadIdx.x];
    __syncthreads();
    const unsigned c = idx / 196;
    const unsigned f = idx % 196;
    const float4* xp = (const float4*)(x + ((size_t)(b * CCH + c) * TT) * HWSZ);
    float4 acc[KBINS];
#pragma unroll
    for (int k = 0; k < KBINS; k++) { acc[k].x = 0.f; acc[k].y = 0.f; acc[k].z = 0.f; acc[k].w = 0.f; }
#pragma unroll 8
    for (int t = 0; t < TT; t++) {
        float4 v = xp[t * 196 + f];
#pragma unroll
        for (int k = 0; k < KBINS; k++) {
            float wk = w[t * KBINS + k];
            acc[k].x += v.x * wk;
            acc[k].y += v.y * wk;
            acc[k].z += v.z * wk;
            acc[k].w += v.w * wk;
        }
    }
    float4* op = (float4*)(out + ((size_t)(b * CCH + c) * KBINS) * HWSZ);
#pragma unroll
    for (int k = 0; k < KBINS; k++) op[k * 196 + f] = acc[k];
}

extern "C" void kernel_launch(void* const* d_in, const int* in_sizes, int n_in,
                              void* d_out, int out_size, void* d_ws, size_t ws_size,
                              hipStream_t stream) {
    const float* x  = (const float*)d_in[0];
    const float* W1 = (const float*)d_in[1];
    const float* b1 = (const float*)d_in[2];
    const float* W2 = (const float*)d_in[3];
    const float* b2 = (const float*)d_in[4];
    float* out = (float*)d_out;

    float* ws     = (float*)d_ws;
    float* pooled = ws;                          // B*T*C   = 65536  [b][t][c]
    float* embds  = pooled + BATCH * TT * CCH;   // B*EMB*T = 8192
    float* nw     = embds + BATCH * EMB * TT;    // B*T*K   = 1024

    pool_kernel<<<BATCH * CCH * TT / 4, 256, 0, stream>>>(x, pooled);
    fc_kernel<<<BATCH * TT, 512, 0, stream>>>(W1, b1, W2, b2, pooled, embds);
    group_kernel<<<BATCH, 256, 0, stream>>>(embds, nw);
    out_kernel<<<BATCH * 392, 128, 0, stream>>>(x, nw, out);
}